// Round 17
// baseline (10209.988 us; speedup 1.0000x reference)
//
#include <hip/hip_runtime.h>

// CharRNN: 3-layer shared-weight LSTM (H=65) over T=4096, B=50, + dense head.
//
// Round-17: TWO SEQUENCES PER BLOCK ON SEPARATE WAVES. 25 blocks x 1024 thr
// (16 waves, 4/SIMD, wpe(4,4) -> 128-VGPR cap). Half h = tid>>9 runs the
// UNMODIFIED R9 pipeline (stid = tid&511) on sequence 2*blk+h: per-thread
// code, registers (~88), and LDS pattern identical to the proven 5.9ms R9.
//   Rationale: R9 = 1,850 issue + 1,600 stall @ 2 waves/SIMD. R12 (2 seqs in
//   the SAME threads) doubled per-wave issue -> null, correctly. Separate
//   waves double per-SIMD issue but 4-way TLP hides the latency-type stall
//   instead of paying it twice -> per-seq round 3,480 -> ~1,700-2,100 cyc.
//   R16 lesson (masked work issues per wave) applied: extras live on
//   within-half waves {1,6}/{3,4} -> one extra COLDOT per SIMD, balanced.

#define HH    65
#define G4    260
#define TT    4096
#define NBLK  25
#define BLOCK 1024
#define DROWS 64

#define KEEP4(v) asm volatile("" : "+v"(v.x), "+v"(v.y), "+v"(v.z), "+v"(v.w))
#define KEEP(s)  asm volatile("" : "+v"(s))

__device__ __forceinline__ float sigm(float x)  { return 1.0f / (1.0f + __expf(-x)); }
__device__ __forceinline__ float tanha(float x) { float e = __expf(2.0f * x); return 1.0f - 2.0f / (e + 1.0f); }

// sum across the 4 lanes of a quad (lane bits 0-1) via DPP; all 4 lanes get total
__device__ __forceinline__ float qsum(float v) {
    int i = __float_as_int(v);
    v += __int_as_float(__builtin_amdgcn_update_dpp(0, i, 0xB1, 0xF, 0xF, true)); // [1,0,3,2]
    i = __float_as_int(v);
    v += __int_as_float(__builtin_amdgcn_update_dpp(0, i, 0x4E, 0xF, 0xF, true)); // [2,3,0,1]
    return v;
}

__global__ void __launch_bounds__(BLOCK)
__attribute__((amdgpu_waves_per_eu(4, 4)))
charrnn_rec(const float* __restrict__ x, const float* __restrict__ W,
            const float* __restrict__ U, const float* __restrict__ bv,
            float* __restrict__ out)
{
    __shared__ __align__(16) float s_hin[2][3][68];    // [half][layer][cell]; row0 = x(t)
    __shared__ __align__(16) float s_hrec[2][3][68];   // [half][layer][cell]
    __shared__ __align__(16) float s_z[2][3][2][256];  // [half][layer][side][col]
    __shared__ float s_parte[2][3][2][4];              // [half][layer][side][col-256]

    const int tid  = threadIdx.x;
    const int h    = tid >> 9;            // sequence half 0/1
    const int stid = tid & 511;           // R9-equivalent thread id within half
    const int lane = tid & 63;
    const int wvh  = (tid >> 6) & 7;      // wave index within half (0..7)

    const int bat = 2 * blockIdx.x + h;
    const float* xb   = x   + (size_t)bat * TT * HH;
    float*       outb = out + (size_t)bat * TT * HH;

    for (int i = tid; i < 2 * 3 * 68; i += BLOCK) { (&s_hin[0][0][0])[i] = 0.0f; (&s_hrec[0][0][0])[i] = 0.0f; }

    const int w    = stid & 3;            // k-window: rows 16w..16w+15 (+ row 64 on w==3)
    const int side = stid >> 8;           // 0 = W (reads hin), 1 = U (reads hrec)
    const int qL   = (stid >> 2) & 63;    // column quad within side
    const int col0 = qL * 4;              // cols col0..col0+3 (0..255)
    const float* M = side ? U : W;

    // 16 float4 weights (R9-proven spelling)
    float4 wa0, wa1, wa2, wa3, wb0, wb1, wb2, wb3,
           wc0, wc1, wc2, wc3, wd0, wd1, wd2, wd3;
#define WLD(v, c, q)                                                          \
    do {                                                                      \
        v.x = M[(16 * w + 4 * (q) + 0) * G4 + col0 + (c)];                    \
        v.y = M[(16 * w + 4 * (q) + 1) * G4 + col0 + (c)];                    \
        v.z = M[(16 * w + 4 * (q) + 2) * G4 + col0 + (c)];                    \
        v.w = M[(16 * w + 4 * (q) + 3) * G4 + col0 + (c)];                    \
        KEEP4(v);                                                             \
    } while (0)
    WLD(wa0, 0, 0); WLD(wa1, 0, 1); WLD(wa2, 0, 2); WLD(wa3, 0, 3);
    WLD(wb0, 1, 0); WLD(wb1, 1, 1); WLD(wb2, 1, 2); WLD(wb3, 1, 3);
    WLD(wc0, 2, 0); WLD(wc1, 2, 1); WLD(wc2, 2, 2); WLD(wc3, 2, 3);
    WLD(wd0, 3, 0); WLD(wd1, 3, 1); WLD(wd2, 3, 2); WLD(wd3, 3, 3);
#undef WLD
    float ws0 = (w == 3) ? M[64 * G4 + col0 + 0] : 0.0f; KEEP(ws0);
    float ws1 = (w == 3) ? M[64 * G4 + col0 + 1] : 0.0f; KEEP(ws1);
    float ws2 = (w == 3) ? M[64 * G4 + col0 + 2] : 0.0f; KEEP(ws2);
    float ws3 = (w == 3) ? M[64 * G4 + col0 + 3] : 0.0f; KEEP(ws3);

    // extra cols 256..259: ONE wave per (half, side), spread across SIMDs:
    //   half0: wvh 1 (side0, SIMD1), wvh 6 (side1, SIMD2)
    //   half1: wvh 3 (side0, SIMD3), wvh 4 (side1, SIMD0)
    // lanes 0..15: col 256+(lane>>2), window w = lane&3 (matches staged H).
    const bool isX = (lane < 16) &&
                     (h == 0 ? (wvh == 1 || wvh == 6) : (wvh == 3 || wvh == 4));
    const int  colX = 256 + ((lane >> 2) & 3);
    float4 e0, e1, e2, e3;
#define ELD(v, q)                                                             \
    do {                                                                      \
        v.x = isX ? M[(16 * w + 4 * (q) + 0) * G4 + colX] : 0.0f;             \
        v.y = isX ? M[(16 * w + 4 * (q) + 1) * G4 + colX] : 0.0f;             \
        v.z = isX ? M[(16 * w + 4 * (q) + 2) * G4 + colX] : 0.0f;             \
        v.w = isX ? M[(16 * w + 4 * (q) + 3) * G4 + colX] : 0.0f;             \
        KEEP4(v);                                                             \
    } while (0)
    ELD(e0, 0); ELD(e1, 1); ELD(e2, 2); ELD(e3, 3);
#undef ELD
    float esc = (isX && w == 3) ? M[64 * G4 + colX] : 0.0f; KEEP(esc);

    // cell role (stid < 195): biases pre-loaded to registers
    const int  cl = stid / 65, n = stid - (stid / 65) * 65;
    const bool isC = (stid < 195);
    const float bz0 = bv[n], bz1 = bv[65 + n], bz2 = bv[130 + n], bz3 = bv[195 + n];
    float creg = 0.0f;

    // x prefetch: stid 447..511 -> pidx 0..64 (per half)
    const bool isP  = (stid >= 447);
    const int  pidx = stid - 447;
    float cur = 0.0f, nxt = 0.0f;
    if (isP) {
        s_hin[h][0][pidx] = xb[pidx];   // x(0)
        cur = xb[HH + pidx];            // x(1)
    }
    __syncthreads();

    for (int r = 0; r < TT + 2; ++r) {
        // ---------------- Phase A ----------------
        if (isP) {  // issue x(r+2) early
            const int tn = r + 2;
            nxt = (tn < TT) ? xb[(size_t)tn * HH + pidx] : 0.0f;
        }
#pragma unroll
        for (int l = 0; l < 3; ++l) {
            if ((unsigned)(r - l) < TT) {
                const float* hb = side ? &s_hrec[h][l][0] : &s_hin[h][l][0];
                const float4* h4 = (const float4*)(hb + 16 * w);   // 16B aligned
                const float4 H0 = h4[0], H1 = h4[1], H2 = h4[2], H3 = h4[3];
                const float  h64 = hb[64];                          // broadcast b32
                float a0, a1, a2, a3;
#define COLDOT(acc, p0, p1, p2, p3, ps)                                       \
    {   float u0, u1;                                                         \
        u0 = H0.x * p0.x;           u1 = H0.y * p0.y;                         \
        u0 = fmaf(H0.z, p0.z, u0);  u1 = fmaf(H0.w, p0.w, u1);                \
        u0 = fmaf(H1.x, p1.x, u0);  u1 = fmaf(H1.y, p1.y, u1);                \
        u0 = fmaf(H1.z, p1.z, u0);  u1 = fmaf(H1.w, p1.w, u1);                \
        u0 = fmaf(H2.x, p2.x, u0);  u1 = fmaf(H2.y, p2.y, u1);                \
        u0 = fmaf(H2.z, p2.z, u0);  u1 = fmaf(H2.w, p2.w, u1);                \
        u0 = fmaf(H3.x, p3.x, u0);  u1 = fmaf(H3.y, p3.y, u1);                \
        u0 = fmaf(H3.z, p3.z, u0);  u1 = fmaf(H3.w, p3.w, u1);                \
        u0 = fmaf(h64, ps, u0);                                               \
        acc = u0 + u1; }
                COLDOT(a0, wa0, wa1, wa2, wa3, ws0)
                COLDOT(a1, wb0, wb1, wb2, wb3, ws1)
                COLDOT(a2, wc0, wc1, wc2, wc3, ws2)
                COLDOT(a3, wd0, wd1, wd2, wd3, ws3)
                a0 = qsum(a0); a1 = qsum(a1); a2 = qsum(a2); a3 = qsum(a3);
                if (w == 0)
                    *(float4*)&s_z[h][l][side][col0] = make_float4(a0, a1, a2, a3);
                if (isX) {
                    float ea;
                    COLDOT(ea, e0, e1, e2, e3, esc)
                    ea = qsum(ea);
                    if ((lane & 3) == 0) s_parte[h][l][side][(lane >> 2) & 3] = ea;
                }
#undef COLDOT
            }
        }
        __syncthreads();

        // ---------------- Phase B: cell updates (per half) ----------------
        if (isC) {
            if ((unsigned)(r - cl) < TT) {
                const float zi = bz0 + s_z[h][cl][0][n]       + s_z[h][cl][1][n];
                const float zf = bz1 + s_z[h][cl][0][65 + n]  + s_z[h][cl][1][65 + n];
                const float zg = bz2 + s_z[h][cl][0][130 + n] + s_z[h][cl][1][130 + n];
                float zo;
                if (n < 61) zo = bz3 + s_z[h][cl][0][195 + n]    + s_z[h][cl][1][195 + n];
                else        zo = bz3 + s_parte[h][cl][0][n - 61] + s_parte[h][cl][1][n - 61];
                const float ig = sigm(zi), fg = sigm(zf), gg = tanha(zg), og = sigm(zo);
                creg = fmaf(fg, creg, ig * gg);
                const float hv = og * tanha(creg);
                s_hrec[h][cl][n] = hv;
                if (cl < 2) s_hin[h][cl + 1][n] = hv;
                else        outb[(size_t)(r - cl) * HH + n] = hv;   // stream h2 to out
            }
        }
        if (isP) {
            if (r + 1 < TT) s_hin[h][0][pidx] = cur;
            cur = nxt;
        }
        __syncthreads();
    }
}

// ---- kernel 2: in-place dense head over d_out: y = h2 @ Wd + bd ----
__global__ void __launch_bounds__(256, 1)
dense_head(float* __restrict__ io, const float* __restrict__ Wd, const float* __restrict__ bd)
{
    __shared__ __align__(16) float s_h[DROWS][68];
    __shared__ float s_wd[HH][HH];
    __shared__ float s_bd[HH];

    const int tid = threadIdx.x;
    float* base = io + (size_t)blockIdx.x * DROWS * HH;

    for (int i = tid; i < DROWS * HH; i += 256) {
        const int row = i / HH, k = i - row * HH;
        s_h[row][k] = base[i];
    }
    for (int i = tid; i < HH * HH; i += 256) (&s_wd[0][0])[i] = Wd[i];
    if (tid < HH) s_bd[tid] = bd[tid];
    __syncthreads();

    for (int u = tid; u < DROWS * HH; u += 256) {
        const int row = u / HH, c = u - row * HH;
        const float4* hp = (const float4*)&s_h[row][0];
        float acc = s_bd[c];
#pragma unroll
        for (int k4 = 0; k4 < 16; ++k4) {
            const float4 hv = hp[k4];
            acc = fmaf(hv.x, s_wd[4 * k4 + 0][c], acc);
            acc = fmaf(hv.y, s_wd[4 * k4 + 1][c], acc);
            acc = fmaf(hv.z, s_wd[4 * k4 + 2][c], acc);
            acc = fmaf(hv.w, s_wd[4 * k4 + 3][c], acc);
        }
        acc = fmaf(s_h[row][64], s_wd[64][c], acc);
        base[u] = acc;   // safe: all reads come from LDS copies
    }
}

extern "C" void kernel_launch(void* const* d_in, const int* in_sizes, int n_in,
                              void* d_out, int out_size, void* d_ws, size_t ws_size,
                              hipStream_t stream)
{
    const float* x  = (const float*)d_in[0];
    const float* W  = (const float*)d_in[1];
    const float* U  = (const float*)d_in[2];
    const float* bv = (const float*)d_in[3];
    const float* Wd = (const float*)d_in[4];
    const float* bd = (const float*)d_in[5];
    float* out = (float*)d_out;

    hipLaunchKernelGGL(charrnn_rec, dim3(NBLK), dim3(BLOCK), 0, stream, x, W, U, bv, out);
    hipLaunchKernelGGL(dense_head, dim3(50 * TT / DROWS), dim3(256), 0, stream, out, Wd, bd);
}

// Round 18
// 5678.489 us; speedup vs baseline: 1.7980x; 1.7980x over previous
//
#include <hip/hip_runtime.h>

// CharRNN: 3-layer shared-weight LSTM (H=65) over T=4096, B=50, + dense head.
//
// Round-18: ROLE-SPLIT WAVES. 50 blocks x 768 threads (12 waves, 3/SIMD,
// wpe(3,3) -> 170-VGPR cap). Gate threads 0..511 are the BYTE-IDENTICAL
// blessed R9 Phase-A pipeline (88 VGPRs granted at 512thr+wpe(2,2)), shed of
// extras/PhaseB/prefetch. Aux waves 8..11 (one per SIMD, ~30 VGPRs):
//   wave 8+cl: Phase B for layer cl (lane n = cell), creg in register
//   wave 11:   x-prefetch (lane=pidx; lane63 also pidx64) + cell-64 B (lanes 0-2)
//   each aux wave: extra col 256+awv on lanes 0..7 (s=lane>>2, w=lane&3)
// Gains: critical-SIMD issue 1850 -> ~1350; 3rd wave/SIMD overlaps phase-
// transition latency. Also the decisive allocator probe at 768 threads.

#define HH    65
#define G4    260
#define TT    4096
#define NB    50
#define BLOCK 768
#define NGATE 512
#define DROWS 64

#define KEEP4(v) asm volatile("" : "+v"(v.x), "+v"(v.y), "+v"(v.z), "+v"(v.w))
#define KEEP(s)  asm volatile("" : "+v"(s))

__device__ __forceinline__ float sigm(float x)  { return 1.0f / (1.0f + __expf(-x)); }
__device__ __forceinline__ float tanha(float x) { float e = __expf(2.0f * x); return 1.0f - 2.0f / (e + 1.0f); }

// sum across the 4 lanes of a quad (lane bits 0-1) via DPP; all 4 lanes get total
__device__ __forceinline__ float qsum(float v) {
    int i = __float_as_int(v);
    v += __int_as_float(__builtin_amdgcn_update_dpp(0, i, 0xB1, 0xF, 0xF, true)); // [1,0,3,2]
    i = __float_as_int(v);
    v += __int_as_float(__builtin_amdgcn_update_dpp(0, i, 0x4E, 0xF, 0xF, true)); // [2,3,0,1]
    return v;
}

__global__ void __launch_bounds__(BLOCK)
__attribute__((amdgpu_waves_per_eu(3, 3)))
charrnn_rec(const float* __restrict__ x, const float* __restrict__ W,
            const float* __restrict__ U, const float* __restrict__ bv,
            float* __restrict__ out)
{
    __shared__ __align__(16) float s_hin[3][68];    // input to layer l (row0 = x(t)); [65..67]=0
    __shared__ __align__(16) float s_hrec[3][68];   // recurrent h per layer
    __shared__ __align__(16) float s_z[3][2][256];  // [layer][side][col] dots, cols 0..255
    __shared__ float s_parte[3][2][4];              // [layer][side][col-256] dots, cols 256..259

    const int bat = blockIdx.x;
    const int tid = threadIdx.x;
    const float* xb   = x   + (size_t)bat * TT * HH;
    float*       outb = out + (size_t)bat * TT * HH;

    for (int i = tid; i < 3 * 68; i += BLOCK) { (&s_hin[0][0])[i] = 0.0f; (&s_hrec[0][0])[i] = 0.0f; }

    const bool isG  = (tid < NGATE);
    const int  atid = tid - NGATE;        // aux id 0..255 (aux threads)
    const int  awv  = (atid >> 6) & 3;    // aux wave 0..3 (block waves 8..11 -> SIMD 0..3)
    const int  al   = atid & 63;          // aux lane

    // ---------------- gate role (tid < 512): EXACT R9 main-dot ----------------
    const int w    = tid & 3;             // k-window: rows 16w..16w+15 (+ row 64 on w==3)
    const int side = tid >> 8;            // 0 = W (reads hin), 1 = U (reads hrec)
    const int col0 = ((tid >> 2) & 63) * 4;
    const float* M = side ? U : W;

    float4 wa0, wa1, wa2, wa3, wb0, wb1, wb2, wb3,
           wc0, wc1, wc2, wc3, wd0, wd1, wd2, wd3;
#define WLD(v, c, q)                                                          \
    do {                                                                      \
        v.x = isG ? M[(16 * w + 4 * (q) + 0) * G4 + col0 + (c)] : 0.0f;       \
        v.y = isG ? M[(16 * w + 4 * (q) + 1) * G4 + col0 + (c)] : 0.0f;       \
        v.z = isG ? M[(16 * w + 4 * (q) + 2) * G4 + col0 + (c)] : 0.0f;       \
        v.w = isG ? M[(16 * w + 4 * (q) + 3) * G4 + col0 + (c)] : 0.0f;       \
        KEEP4(v);                                                             \
    } while (0)
    WLD(wa0, 0, 0); WLD(wa1, 0, 1); WLD(wa2, 0, 2); WLD(wa3, 0, 3);
    WLD(wb0, 1, 0); WLD(wb1, 1, 1); WLD(wb2, 1, 2); WLD(wb3, 1, 3);
    WLD(wc0, 2, 0); WLD(wc1, 2, 1); WLD(wc2, 2, 2); WLD(wc3, 2, 3);
    WLD(wd0, 3, 0); WLD(wd1, 3, 1); WLD(wd2, 3, 2); WLD(wd3, 3, 3);
#undef WLD
    float ws0 = (isG && w == 3) ? M[64 * G4 + col0 + 0] : 0.0f; KEEP(ws0);
    float ws1 = (isG && w == 3) ? M[64 * G4 + col0 + 1] : 0.0f; KEEP(ws1);
    float ws2 = (isG && w == 3) ? M[64 * G4 + col0 + 2] : 0.0f; KEEP(ws2);
    float ws3 = (isG && w == 3) ? M[64 * G4 + col0 + 3] : 0.0f; KEEP(ws3);

    // ---------------- aux roles (tid >= 512) ----------------
    // extras: lanes 0..7 of each aux wave; col 256+awv; es = lane>>2 (side), ew = lane&3
    const bool isE = (!isG) && (al < 8);
    const int  es  = (al >> 2) & 1;
    const int  ew  = al & 3;
    const int  colE = 256 + awv;
    const float* ME = es ? U : W;
    float4 e0, e1, e2, e3;
#define ELD(v, q)                                                             \
    do {                                                                      \
        v.x = isE ? ME[(16 * ew + 4 * (q) + 0) * G4 + colE] : 0.0f;           \
        v.y = isE ? ME[(16 * ew + 4 * (q) + 1) * G4 + colE] : 0.0f;           \
        v.z = isE ? ME[(16 * ew + 4 * (q) + 2) * G4 + colE] : 0.0f;           \
        v.w = isE ? ME[(16 * ew + 4 * (q) + 3) * G4 + colE] : 0.0f;           \
        KEEP4(v);                                                             \
    } while (0)
    ELD(e0, 0); ELD(e1, 1); ELD(e2, 2); ELD(e3, 3);
#undef ELD
    float esc = (isE && ew == 3) ? ME[64 * G4 + colE] : 0.0f; KEEP(esc);

    // Phase B: waves 8..10 -> layer awv, cell al (0..63); wave 11 lanes 0..2 -> layer al, cell 64
    const bool isB  = (!isG) && (awv < 3);
    const bool isB64 = (!isG) && (awv == 3) && (al < 3);
    const int  cl = isB ? awv : (isB64 ? al : 0);
    const int  cn = isB ? al : 64;
    const bool anyB = isB || isB64;
    const float bz0 = anyB ? bv[cn]       : 0.0f;
    const float bz1 = anyB ? bv[65 + cn]  : 0.0f;
    const float bz2 = anyB ? bv[130 + cn] : 0.0f;
    const float bz3 = anyB ? bv[195 + cn] : 0.0f;
    float creg = 0.0f;

    // prefetch: wave 11 lanes 0..63 -> pidx = al; lane 63 also handles pidx 64
    const bool isP  = (!isG) && (awv == 3);
    const bool isP2 = isP && (al == 63);
    const int  pidx = al;
    float cur0 = 0.0f, nxt0 = 0.0f, cur1 = 0.0f, nxt1 = 0.0f;
    if (isP) {
        s_hin[0][pidx] = xb[pidx];
        cur0 = xb[HH + pidx];
        if (isP2) { s_hin[0][64] = xb[64]; cur1 = xb[HH + 64]; }
    }
    __syncthreads();

    for (int r = 0; r < TT + 2; ++r) {
        // ---------------- Phase A ----------------
        if (isP) {  // issue x(r+2) early
            const int tn = r + 2;
            nxt0 = (tn < TT) ? xb[(size_t)tn * HH + pidx] : 0.0f;
            if (isP2) nxt1 = (tn < TT) ? xb[(size_t)tn * HH + 64] : 0.0f;
        }
        if (isG) {
#pragma unroll
            for (int l = 0; l < 3; ++l) {
                if ((unsigned)(r - l) < TT) {
                    const float* hb = side ? &s_hrec[l][0] : &s_hin[l][0];
                    const float4* h4 = (const float4*)(hb + 16 * w);
                    const float4 H0 = h4[0], H1 = h4[1], H2 = h4[2], H3 = h4[3];
                    const float  h64 = hb[64];
                    float a0, a1, a2, a3;
#define COLDOT(acc, p0, p1, p2, p3, ps)                                       \
    {   float u0, u1;                                                         \
        u0 = H0.x * p0.x;           u1 = H0.y * p0.y;                         \
        u0 = fmaf(H0.z, p0.z, u0);  u1 = fmaf(H0.w, p0.w, u1);                \
        u0 = fmaf(H1.x, p1.x, u0);  u1 = fmaf(H1.y, p1.y, u1);                \
        u0 = fmaf(H1.z, p1.z, u0);  u1 = fmaf(H1.w, p1.w, u1);                \
        u0 = fmaf(H2.x, p2.x, u0);  u1 = fmaf(H2.y, p2.y, u1);                \
        u0 = fmaf(H2.z, p2.z, u0);  u1 = fmaf(H2.w, p2.w, u1);                \
        u0 = fmaf(H3.x, p3.x, u0);  u1 = fmaf(H3.y, p3.y, u1);                \
        u0 = fmaf(H3.z, p3.z, u0);  u1 = fmaf(H3.w, p3.w, u1);                \
        u0 = fmaf(h64, ps, u0);                                               \
        acc = u0 + u1; }
                    COLDOT(a0, wa0, wa1, wa2, wa3, ws0)
                    COLDOT(a1, wb0, wb1, wb2, wb3, ws1)
                    COLDOT(a2, wc0, wc1, wc2, wc3, ws2)
                    COLDOT(a3, wd0, wd1, wd2, wd3, ws3)
                    a0 = qsum(a0); a1 = qsum(a1); a2 = qsum(a2); a3 = qsum(a3);
                    if (w == 0)
                        *(float4*)&s_z[l][side][col0] = make_float4(a0, a1, a2, a3);
                }
            }
        } else if (isE) {
#pragma unroll
            for (int l = 0; l < 3; ++l) {
                if ((unsigned)(r - l) < TT) {
                    const float* hb = es ? &s_hrec[l][0] : &s_hin[l][0];
                    const float4* h4 = (const float4*)(hb + 16 * ew);
                    const float4 H0 = h4[0], H1 = h4[1], H2 = h4[2], H3 = h4[3];
                    const float  h64 = hb[64];
                    float ea;
                    COLDOT(ea, e0, e1, e2, e3, esc)
                    ea = qsum(ea);                 // quad-reduce over ew (4 lanes, same es)
                    if (ew == 0) s_parte[l][es][awv] = ea;
                }
            }
#undef COLDOT
        }
        __syncthreads();

        // ---------------- Phase B (aux waves) ----------------
        if (anyB) {
            if ((unsigned)(r - cl) < TT) {
                const float zi = bz0 + s_z[cl][0][cn]       + s_z[cl][1][cn];
                const float zf = bz1 + s_z[cl][0][65 + cn]  + s_z[cl][1][65 + cn];
                const float zg = bz2 + s_z[cl][0][130 + cn] + s_z[cl][1][130 + cn];
                float zo;
                if (cn < 61) zo = bz3 + s_z[cl][0][195 + cn]    + s_z[cl][1][195 + cn];
                else         zo = bz3 + s_parte[cl][0][cn - 61] + s_parte[cl][1][cn - 61];
                const float ig = sigm(zi), fg = sigm(zf), gg = tanha(zg), og = sigm(zo);
                creg = fmaf(fg, creg, ig * gg);
                const float h = og * tanha(creg);
                s_hrec[cl][cn] = h;
                if (cl < 2) s_hin[cl + 1][cn] = h;
                else        outb[(size_t)(r - cl) * HH + cn] = h;   // stream h2 to out
            }
        }
        if (isP) {
            if (r + 1 < TT) {
                s_hin[0][pidx] = cur0;
                if (isP2) s_hin[0][64] = cur1;
            }
            cur0 = nxt0; cur1 = nxt1;
        }
        __syncthreads();
    }
}

// ---- kernel 2: in-place dense head over d_out: y = h2 @ Wd + bd ----
__global__ void __launch_bounds__(256, 1)
dense_head(float* __restrict__ io, const float* __restrict__ Wd, const float* __restrict__ bd)
{
    __shared__ __align__(16) float s_h[DROWS][68];
    __shared__ float s_wd[HH][HH];
    __shared__ float s_bd[HH];

    const int tid = threadIdx.x;
    float* base = io + (size_t)blockIdx.x * DROWS * HH;

    for (int i = tid; i < DROWS * HH; i += 256) {
        const int row = i / HH, k = i - row * HH;
        s_h[row][k] = base[i];
    }
    for (int i = tid; i < HH * HH; i += 256) (&s_wd[0][0])[i] = Wd[i];
    if (tid < HH) s_bd[tid] = bd[tid];
    __syncthreads();

    for (int u = tid; u < DROWS * HH; u += 256) {
        const int row = u / HH, c = u - row * HH;
        const float4* hp = (const float4*)&s_h[row][0];
        float acc = s_bd[c];
#pragma unroll
        for (int k4 = 0; k4 < 16; ++k4) {
            const float4 hv = hp[k4];
            acc = fmaf(hv.x, s_wd[4 * k4 + 0][c], acc);
            acc = fmaf(hv.y, s_wd[4 * k4 + 1][c], acc);
            acc = fmaf(hv.z, s_wd[4 * k4 + 2][c], acc);
            acc = fmaf(hv.w, s_wd[4 * k4 + 3][c], acc);
        }
        acc = fmaf(s_h[row][64], s_wd[64][c], acc);
        base[u] = acc;   // safe: all reads come from LDS copies
    }
}

extern "C" void kernel_launch(void* const* d_in, const int* in_sizes, int n_in,
                              void* d_out, int out_size, void* d_ws, size_t ws_size,
                              hipStream_t stream)
{
    const float* x  = (const float*)d_in[0];
    const float* W  = (const float*)d_in[1];
    const float* U  = (const float*)d_in[2];
    const float* bv = (const float*)d_in[3];
    const float* Wd = (const float*)d_in[4];
    const float* bd = (const float*)d_in[5];
    float* out = (float*)d_out;

    hipLaunchKernelGGL(charrnn_rec, dim3(NB), dim3(BLOCK), 0, stream, x, W, U, bv, out);
    hipLaunchKernelGGL(dense_head, dim3(NB * TT / DROWS), dim3(256), 0, stream, out, Wd, bd);
}